// Round 1
// baseline (83.634 us; speedup 1.0000x reference)
//
#include <hip/hip_runtime.h>
#include <stdint.h>

#define NRAYS 262144

// sdf(p) = sqrt(|p|^2 + 1e-12) - 0.5, exact numpy op order, no contraction.
__device__ __forceinline__ float sdf_eval(float px, float py, float pz) {
#pragma clang fp contract(off)
    float s2 = px * px + py * py + pz * pz;   // ((x^2 + y^2) + z^2) like jnp.sum
    return __fsqrt_rn(s2 + 1e-12f) - 0.5f;
}

// zpred from the reference secant: zl - sl*(zh-zl)/where(den==0,1,den)
__device__ __forceinline__ float zpred_f(float sl, float sh, float zl, float zh) {
#pragma clang fp contract(off)
    float den = sh - sl;
    den = (den == 0.0f) ? 1.0f : den;
    return zl - __fdiv_rn(sl * (zh - zl), den);
}

__global__ __launch_bounds__(256) void raytrace_kernel(
    const float* __restrict__ cam,
    const float* __restrict__ dirs,
    const void* __restrict__ maskp,
    float* __restrict__ out)
{
#pragma clang fp contract(off)
    const int i = blockIdx.x * 256 + threadIdx.x;
    if (i >= NRAYS) return;   // N divisible by 256; all lanes active below

    // ---- object_mask storage detection (wave-uniform, redundant per wave) ----
    // bool input may arrive as int32 {0,1}, float32 {0.0,1.0} (bits 0x3F800000),
    // or raw 1-byte bools. int32 and float32 are both handled by (int != 0);
    // byte-packed storage shows int values outside {0,1,0x3F800000}.
    const int* mi = (const int*)maskp;
    const int lane = threadIdx.x & 63;
    bool clean = true;
#pragma unroll
    for (int k = 0; k < 4; ++k) {
        int v = mi[lane + 64 * k];            // 256 ints = 1024 B, in-bounds for all layouts
        clean = clean && (v == 0 || v == 1 || v == 0x3F800000);
    }
    unsigned long long bal = __ballot(clean);
    const bool byte_packed = (bal != 0xFFFFFFFFFFFFFFFFull);
    const bool obj = byte_packed ? (((const unsigned char*)maskp)[i] != 0)
                                 : (mi[i] != 0);

    // ---- load ray ----
    const float ox = cam[3 * i], oy = cam[3 * i + 1], oz = cam[3 * i + 2];
    const float dx = dirs[3 * i], dy = dirs[3 * i + 1], dz = dirs[3 * i + 2];

    // ---- _sphere_intersect(o, d, R_BOUND=1.0) ----
    float a = dx * dx + dy * dy + dz * dz;
    float b = 2.0f * (ox * dx + oy * dy + oz * dz);
    float c = (ox * ox + oy * oy + oz * oz) - 1.0f;          // r*r = 1.0
    float under = b * b - (4.0f * a) * c;                     // (b*b) - ((4*a)*c)
    const bool mask = under > 0.0f;
    float sq = __fsqrt_rn(fmaxf(under, 0.0f));
    float nearv = fmaxf(mask ? (-sq - b) * 0.5f : 0.0f, 0.01f);
    float farv  = fmaxf(mask ? ( sq - b) * 0.5f : 0.0f, 0.01f);

    // ---- _sphere_tracing ----
    bool unf_s = mask, unf_e = mask;
    float acc_s = nearv, acc_e = farv;
    float csx = mask ? (ox + nearv * dx) : 0.0f;
    float csy = mask ? (oy + nearv * dy) : 0.0f;
    float csz = mask ? (oz + nearv * dz) : 0.0f;
    float cex = mask ? (ox + farv * dx) : 0.0f;
    float cey = mask ? (oy + farv * dy) : 0.0f;
    float cez = mask ? (oz + farv * dz) : 0.0f;
    float next_s = unf_s ? sdf_eval(csx, csy, csz) : 0.0f;
    float next_e = unf_e ? sdf_eval(cex, cey, cez) : 0.0f;

    for (int it = 0; it < 10; ++it) {
        // _upd_mask
        float cs = unf_s ? next_s : 0.0f;
        cs = (cs <= 5e-5f) ? 0.0f : cs;
        unf_s = unf_s && (cs > 5e-5f);
        float ce = unf_e ? next_e : 0.0f;
        ce = (ce <= 5e-5f) ? 0.0f : ce;
        unf_e = unf_e && (ce > 5e-5f);

        acc_s = acc_s + cs;
        acc_e = acc_e - ce;
        csx = ox + acc_s * dx; csy = oy + acc_s * dy; csz = oz + acc_s * dz;
        cex = ox + acc_e * dx; cey = oy + acc_e * dy; cez = oz + acc_e * dz;
        next_s = unf_s ? sdf_eval(csx, csy, csz) : 0.0f;
        next_e = unf_e ? sdf_eval(cex, cey, cez) : 0.0f;

        // LINE_STEP_ITERS = 1, step = 0.5
        bool nps = next_s < 0.0f;
        bool npe = next_e < 0.0f;
        if (nps) {
            acc_s = acc_s - 0.5f * cs;
            csx = ox + acc_s * dx; csy = oy + acc_s * dy; csz = oz + acc_s * dz;
            next_s = sdf_eval(csx, csy, csz);
        }
        if (npe) {
            acc_e = acc_e + 0.5f * ce;
            cex = ox + acc_e * dx; cey = oy + acc_e * dy; cez = oz + acc_e * dz;
            next_e = sdf_eval(cex, cey, cez);
        }
        bool ok = acc_s < acc_e;
        unf_s = unf_s && ok;
        unf_e = unf_e && ok;
    }
    { // trailing _upd_mask (mask update only)
        float cs = unf_s ? next_s : 0.0f;
        cs = (cs <= 5e-5f) ? 0.0f : cs;
        unf_s = unf_s && (cs > 5e-5f);
        float ce = unf_e ? next_e : 0.0f;
        ce = (ce <= 5e-5f) ? 0.0f : ce;
        unf_e = unf_e && (ce > 5e-5f);
    }

    const bool net0 = (acc_s < acc_e);
    const bool smask = unf_s;
    const float smin = smask ? acc_s : 0.0f;
    const float smax = smask ? acc_e : 0.0f;

    // ---- _ray_sampler: 100 steps, sqrt-free classification ----
    // sval<0  <=> v <  0.25f            (exact for correctly-rounded sqrt)
    // sval==0 <=> v in {0x3E800000, 0x3E800001}
    const float diff = smax - smin;       // (smax - smin)
    const float dt = 1.0f / 99.0f;        // jnp.linspace step
    const float ZERO_HI = __uint_as_float(0x3E800001u);
    int indNeg = -1, indZero = -1, omin = 0;
    float bestv = 3.4e38f;
    for (int k = 0; k < 100; ++k) {
        float t = (float)k * dt;
        float itv = smin + t * diff;
        float px = ox + dx * itv;
        float py = oy + dy * itv;
        float pz = oz + dz * itv;
        float v = (px * px + py * py + pz * pz) + 1e-12f;
        if (v < bestv) { bestv = v; omin = k; }     // first strict min, like np.argmin
        if (v < 0.25f) {
            if (indNeg < 0) indNeg = k;
        } else if (v <= ZERO_HI) {
            if (indZero < 0) indZero = k;
        }
    }
    const bool hasNeg = (indNeg >= 0);               // == net_surface (sval[ind] < 0)
    const int ind = hasNeg ? indNeg : (indZero >= 0 ? indZero : 99);
    const int ilow = (ind > 0) ? (ind - 1) : 0;

    // intervals[] recomputed with identical op order as the loop
    float tI = (float)ind * dt;   float itvI = smin + tI * diff;
    float tL = (float)ilow * dt;  float itvL = smin + tL * diff;
    float pIx = ox + dx * itvI, pIy = oy + dy * itvI, pIz = oz + dz * itvI;

    float ptsx = pIx, ptsy = pIy, ptsz = pIz;
    float dist = itvI;

    const bool p_out = smask && !(obj && hasNeg);
    if (p_out) {
        float tO = (float)omin * dt;  float itvO = smin + tO * diff;
        ptsx = ox + dx * itvO; ptsy = oy + dy * itvO; ptsz = oz + dz * itvO;
        dist = itvO;
    }

    // ---- _secant (computed unconditionally in the reference) ----
    float pLx = ox + dx * itvL, pLy = oy + dy * itvL, pLz = oz + dz * itvL;
    float s_low  = sdf_eval(pLx, pLy, pLz);
    float s_high = sdf_eval(pIx, pIy, pIz);
    float z_low = itvL, z_high = itvI;
    float z = zpred_f(s_low, s_high, z_low, z_high);
    for (int q = 0; q < 8; ++q) {
        float s = sdf_eval(ox + z * dx, oy + z * dy, oz + z * dz);
        if (s > 0.0f) { z_low = z;  s_low = s; }
        if (s < 0.0f) { z_high = z; s_high = s; }
        z = zpred_f(s_low, s_high, z_low, z_high);
    }
    const bool sec = smask && hasNeg && obj;
    if (sec) {
        ptsx = ox + z * dx; ptsy = oy + z * dy; ptsz = oz + z * dz;
        dist = z;
    }

    // ---- final merge & store ----
    float outx = smask ? ptsx : csx;
    float outy = smask ? ptsy : csy;
    float outz = smask ? ptsz : csz;
    float outnet = smask ? (hasNeg ? 1.0f : 0.0f) : (net0 ? 1.0f : 0.0f);
    float outdist = smask ? dist : acc_s;

    out[3 * i]     = outx;
    out[3 * i + 1] = outy;
    out[3 * i + 2] = outz;
    out[3 * NRAYS + i] = outnet;
    out[4 * NRAYS + i] = outdist;
}

extern "C" void kernel_launch(void* const* d_in, const int* in_sizes, int n_in,
                              void* d_out, int out_size, void* d_ws, size_t ws_size,
                              hipStream_t stream) {
    const float* cam  = (const float*)d_in[0];
    const float* dirs = (const float*)d_in[1];
    const void* maskp = d_in[2];
    float* out = (float*)d_out;
    dim3 grid(NRAYS / 256), block(256);
    raytrace_kernel<<<grid, block, 0, stream>>>(cam, dirs, maskp, out);
}

// Round 2
// 68.834 us; speedup vs baseline: 1.2150x; 1.2150x over previous
//
#include <hip/hip_runtime.h>
#include <stdint.h>

#define NRAYS 262144
#define DT (1.0f/99.0f)

// ---------- exact-order helpers (bit-exact vs numpy reference) ----------

__device__ __forceinline__ float sdf_rn(float px, float py, float pz) {
#pragma clang fp contract(off)
    float s2 = px * px + py * py + pz * pz;
    return __fsqrt_rn(s2 + 1e-12f) - 0.5f;
}

struct SampleE { float itv, px, py, pz, v; };

// Sample k of the ray sampler, computed in exact reference op order.
// numpy linspace forces t[99] = 1.0 exactly (endpoint=True).
__device__ __forceinline__ SampleE eval_k(int k, float smin, float diff,
                                          float ox, float oy, float oz,
                                          float dx, float dy, float dz) {
#pragma clang fp contract(off)
    float t = (k == 99) ? 1.0f : (float)k * DT;
    float itv = smin + t * diff;
    float px = ox + dx * itv;
    float py = oy + dy * itv;
    float pz = oz + dz * itv;
    float v = ((px * px + py * py) + pz * pz) + 1e-12f;
    SampleE e; e.itv = itv; e.px = px; e.py = py; e.pz = pz; e.v = v;
    return e;
}

// ---------- fast-path helpers (continuous outputs only: secant z) ----------

__device__ __forceinline__ float fast_div(float n, float d) {
    float r = __builtin_amdgcn_rcpf(d);
    r = r * (2.0f - d * r);          // 1 Newton step
    return n * r;
}

__device__ __forceinline__ float sdf_fast(float px, float py, float pz) {
    float s2 = fmaf(pz, pz, fmaf(py, py, px * px)) + 1e-12f;
    return __builtin_amdgcn_sqrtf(s2) - 0.5f;
}

__device__ __forceinline__ float zpred_fast(float sl, float sh, float zl, float zh) {
    float den = sh - sl;
    den = (den == 0.0f) ? 1.0f : den;
    return zl - fast_div(sl * (zh - zl), den);
}

__global__ __launch_bounds__(256) void raytrace_kernel(
    const float* __restrict__ cam,
    const float* __restrict__ dirs,
    const void* __restrict__ maskp,
    float* __restrict__ out)
{
#pragma clang fp contract(off)
    const int i = blockIdx.x * 256 + threadIdx.x;

    // ---- object_mask storage probe (int32 / float32 / byte-packed bool) ----
    const int* mi = (const int*)maskp;
    const int lane = threadIdx.x & 63;
    bool clean = true;
#pragma unroll
    for (int k = 0; k < 4; ++k) {
        int v = mi[lane + 64 * k];
        clean = clean && (v == 0 || v == 1 || v == 0x3F800000);
    }
    unsigned long long bal = __ballot(clean);
    const bool byte_packed = (bal != 0xFFFFFFFFFFFFFFFFull);
    const bool obj = byte_packed ? (((const unsigned char*)maskp)[i] != 0)
                                 : (mi[i] != 0);

    // ---- load ray ----
    const float ox = cam[3 * i], oy = cam[3 * i + 1], oz = cam[3 * i + 2];
    const float dx = dirs[3 * i], dy = dirs[3 * i + 1], dz = dirs[3 * i + 2];

    // ---- _sphere_intersect (exact) ----
    float a  = dx * dx + dy * dy + dz * dz;
    float ob = ox * dx + oy * dy + oz * dz;
    float b  = 2.0f * ob;
    float oo = ox * ox + oy * oy + oz * oz;
    float c  = oo - 1.0f;
    float under = b * b - (4.0f * a) * c;
    const bool mask = under > 0.0f;
    float sq = __fsqrt_rn(fmaxf(under, 0.0f));
    float nearv = fmaxf(mask ? (-sq - b) * 0.5f : 0.0f, 0.01f);
    float farv  = fmaxf(mask ? ( sq - b) * 0.5f : 0.0f, 0.01f);

    // ---- _sphere_tracing (exact; early-break on wave-wide fixpoint) ----
    bool unf_s = mask, unf_e = mask;
    float acc_s = nearv, acc_e = farv;
    float csx = mask ? (ox + nearv * dx) : 0.0f;
    float csy = mask ? (oy + nearv * dy) : 0.0f;
    float csz = mask ? (oz + nearv * dz) : 0.0f;
    float cex = mask ? (ox + farv * dx) : 0.0f;
    float cey = mask ? (oy + farv * dy) : 0.0f;
    float cez = mask ? (oz + farv * dz) : 0.0f;
    float next_s = unf_s ? sdf_rn(csx, csy, csz) : 0.0f;
    float next_e = unf_e ? sdf_rn(cex, cey, cez) : 0.0f;

    for (int it = 0; it < 10; ++it) {
        float cs = unf_s ? next_s : 0.0f;
        cs = (cs <= 5e-5f) ? 0.0f : cs;
        unf_s = unf_s && (cs > 5e-5f);
        float ce = unf_e ? next_e : 0.0f;
        ce = (ce <= 5e-5f) ? 0.0f : ce;
        unf_e = unf_e && (ce > 5e-5f);

        acc_s = acc_s + cs;
        acc_e = acc_e - ce;
        csx = ox + acc_s * dx; csy = oy + acc_s * dy; csz = oz + acc_s * dz;
        cex = ox + acc_e * dx; cey = oy + acc_e * dy; cez = oz + acc_e * dz;
        next_s = unf_s ? sdf_rn(csx, csy, csz) : 0.0f;
        next_e = unf_e ? sdf_rn(cex, cey, cez) : 0.0f;

        bool nps = next_s < 0.0f;
        bool npe = next_e < 0.0f;
        if (nps) {
            acc_s = acc_s - 0.5f * cs;
            csx = ox + acc_s * dx; csy = oy + acc_s * dy; csz = oz + acc_s * dz;
            next_s = sdf_rn(csx, csy, csz);
        }
        if (npe) {
            acc_e = acc_e + 0.5f * ce;
            cex = ox + acc_e * dx; cey = oy + acc_e * dy; cez = oz + acc_e * dz;
            next_e = sdf_rn(cex, cey, cez);
        }
        bool ok = acc_s < acc_e;
        unf_s = unf_s && ok;
        unf_e = unf_e && ok;

        // Converged state is a fixpoint (cs=ce=0, next=0): skipping the
        // remaining iterations is bit-exact once no lane is unfinished.
        if (!__any(unf_s || unf_e)) break;
    }
    { // trailing _upd_mask (mask bits only)
        float cs = unf_s ? next_s : 0.0f;
        cs = (cs <= 5e-5f) ? 0.0f : cs;
        unf_s = unf_s && (cs > 5e-5f);
        float ce = unf_e ? next_e : 0.0f;
        ce = (ce <= 5e-5f) ? 0.0f : ce;
        unf_e = unf_e && (ce > 5e-5f);
    }

    const bool net0 = (acc_s < acc_e);
    const bool smask = unf_s;
    const float smin = smask ? acc_s : 0.0f;
    const float smax = smask ? acc_e : 0.0f;
    const float diff = smax - smin;
    const float denk = diff * DT;

    // ---- analytic sampler: v(t)=a t^2 + 2 ob t + (oo+1e-12) is a parabola.
    // Find argmin / first-negative indices analytically, verify with exact
    // reference-order v at a small window; rare fallback = full exact scan.
    const float ZERO_HI = __uint_as_float(0x3E800001u); // v==0.25 +1ulp <=> sval==0
    float ptsx = 0.0f, ptsy = 0.0f, ptsz = 0.0f, dist = 0.0f;
    bool hasNeg = false;

    if (__any(smask)) {
        float tstar = -ob / a;                      // parabola vertex (param space)
        float kf = (diff > 0.0f) ? (tstar - smin) / denk : 0.0f;
        kf = fminf(fmaxf(kf, 0.0f), 99.0f);
        int kv = (int)floorf(kf + 0.5f);
        int w0 = kv - 1; if (w0 < 0) w0 = 0;
        int w1 = kv + 1; if (w1 > 99) w1 = 99;

        int omin = w0; float vmin = 3.4e38f;
        for (int k = w0; k <= w1; ++k) {            // exact sampled min (parabola
            float vk = eval_k(k, smin, diff, ox, oy, oz, dx, dy, dz).v;
            if (vk < vmin) { vmin = vk; omin = k; } // => min is in this window)
        }
        hasNeg = vmin < 0.25f;                      // == (min sampled sval < 0), exact

        int ind;
        if (hasNeg) {
            float v0 = eval_k(0, smin, diff, ox, oy, oz, dx, dy, dz).v;
            if (v0 < 0.25f) {
                ind = 0;
            } else {
                // left root of v(t) = 0.25, mapped to index space
                float cs25 = (oo + 1e-12f) - 0.25f;
                float disc = ob * ob - a * cs25;
                float r0 = (-ob - __fsqrt_rn(fmaxf(disc, 0.0f))) / a;
                float kf0 = (r0 - smin) / denk;
                if (!(kf0 >= 1.0f)) kf0 = 1.0f;     // NaN-safe clamp
                if (kf0 > 99.0f) kf0 = 99.0f;
                int start = (int)kf0 - 2; if (start < 1) start = 1;
                int kend = start + 5; if (kend > 99) kend = 99;
                int found = -1;
                float vprev = eval_k(start - 1, smin, diff, ox, oy, oz, dx, dy, dz).v;
                for (int k = start; k <= kend; ++k) {
                    float vk = eval_k(k, smin, diff, ox, oy, oz, dx, dy, dz).v;
                    if (vprev >= 0.25f && vk < 0.25f) { found = k; break; }
                    vprev = vk;
                }
                if (found < 0) {                    // analytic window missed: exact scan
                    for (int k = 1; k <= 99; ++k) {
                        if (eval_k(k, smin, diff, ox, oy, oz, dx, dy, dz).v < 0.25f) {
                            found = k; break;
                        }
                    }
                    if (found < 0) found = omin;    // unreachable
                }
                ind = found;
            }
        } else if (vmin <= ZERO_HI) {               // sval==0 samples exist (~never)
            ind = 99;
            for (int k = 0; k <= 99; ++k) {
                if (eval_k(k, smin, diff, ox, oy, oz, dx, dy, dz).v <= ZERO_HI) {
                    ind = k; break;
                }
            }
        } else {
            ind = 99;                               // all sval > 0 -> last index
        }

        const int ilow = (ind > 0) ? ind - 1 : 0;
        SampleE eI = eval_k(ind,  smin, diff, ox, oy, oz, dx, dy, dz);
        SampleE eL = eval_k(ilow, smin, diff, ox, oy, oz, dx, dy, dz);

        ptsx = eI.px; ptsy = eI.py; ptsz = eI.pz;
        dist = eI.itv;

        const bool p_out = smask && !(obj && hasNeg);
        if (p_out) {
            SampleE eO = eval_k(omin, smin, diff, ox, oy, oz, dx, dy, dz);
            ptsx = eO.px; ptsy = eO.py; ptsz = eO.pz;
            dist = eO.itv;
        }

        // ---- secant: continuous output only -> native sqrt + rcp division ----
        const bool sec = smask && hasNeg && obj;
        if (__any(sec)) {
            float s_low  = sdf_fast(eL.px, eL.py, eL.pz);
            float s_high = sdf_fast(eI.px, eI.py, eI.pz);
            float z_low = eL.itv, z_high = eI.itv;
            float z = zpred_fast(s_low, s_high, z_low, z_high);
            for (int q = 0; q < 8; ++q) {
                float zx = ox + z * dx, zy = oy + z * dy, zz = oz + z * dz;
                float s = sdf_fast(zx, zy, zz);
                if (s > 0.0f) { z_low = z;  s_low = s; }
                if (s < 0.0f) { z_high = z; s_high = s; }
                z = zpred_fast(s_low, s_high, z_low, z_high);
            }
            if (sec) {
                ptsx = ox + z * dx; ptsy = oy + z * dy; ptsz = oz + z * dz;
                dist = z;
            }
        }
    }

    // ---- final merge & store ----
    float outx = smask ? ptsx : csx;
    float outy = smask ? ptsy : csy;
    float outz = smask ? ptsz : csz;
    float outnet = smask ? (hasNeg ? 1.0f : 0.0f) : (net0 ? 1.0f : 0.0f);
    float outdist = smask ? dist : acc_s;

    out[3 * i]     = outx;
    out[3 * i + 1] = outy;
    out[3 * i + 2] = outz;
    out[3 * NRAYS + i] = outnet;
    out[4 * NRAYS + i] = outdist;
}

extern "C" void kernel_launch(void* const* d_in, const int* in_sizes, int n_in,
                              void* d_out, int out_size, void* d_ws, size_t ws_size,
                              hipStream_t stream) {
    const float* cam  = (const float*)d_in[0];
    const float* dirs = (const float*)d_in[1];
    const void* maskp = d_in[2];
    float* out = (float*)d_out;
    dim3 grid(NRAYS / 256), block(256);
    raytrace_kernel<<<grid, block, 0, stream>>>(cam, dirs, maskp, out);
}

// Round 3
// 68.474 us; speedup vs baseline: 1.2214x; 1.0053x over previous
//
#include <hip/hip_runtime.h>
#include <stdint.h>

#define NRAYS 262144
#define DT (1.0f/99.0f)

// ---------- exact-order helpers (bit-exact vs numpy reference) ----------

__device__ __forceinline__ float sdf_rn(float px, float py, float pz) {
#pragma clang fp contract(off)
    float s2 = px * px + py * py + pz * pz;
    return __fsqrt_rn(s2 + 1e-12f) - 0.5f;
}

struct SampleE { float itv, px, py, pz, v; };

// Sample k of the ray sampler, exact reference op order.
// numpy linspace endpoint: t[99] = 1.0 exactly.
__device__ __forceinline__ SampleE eval_k(int k, float smin, float diff,
                                          float ox, float oy, float oz,
                                          float dx, float dy, float dz) {
#pragma clang fp contract(off)
    float t = (k == 99) ? 1.0f : (float)k * DT;
    float itv = smin + t * diff;
    float px = ox + dx * itv;
    float py = oy + dy * itv;
    float pz = oz + dz * itv;
    float v = ((px * px + py * py) + pz * pz) + 1e-12f;
    SampleE e; e.itv = itv; e.px = px; e.py = py; e.pz = pz; e.v = v;
    return e;
}

// ---------- fast-path helpers ----------

__device__ __forceinline__ float fast_div(float n, float d) {
    float r = __builtin_amdgcn_rcpf(d);
    r = r * (2.0f - d * r);          // 1 Newton step
    return n * r;
}

__device__ __forceinline__ float sdf_fast(float px, float py, float pz) {
    float s2 = fmaf(pz, pz, fmaf(py, py, px * px)) + 1e-12f;
    return __builtin_amdgcn_sqrtf(s2) - 0.5f;
}

__device__ __forceinline__ float zpred_fast(float sl, float sh, float zl, float zh) {
    float den = sh - sl;
    den = (den == 0.0f) ? 1.0f : den;
    return zl - fast_div(sl * (zh - zl), den);
}

__global__ __launch_bounds__(256) void raytrace_kernel(
    const float* __restrict__ cam,
    const float* __restrict__ dirs,
    const void* __restrict__ maskp,
    float* __restrict__ out)
{
#pragma clang fp contract(off)
    const int i = blockIdx.x * 256 + threadIdx.x;

    // ---- object_mask storage probe (int32 / float32 / byte-packed bool) ----
    const int* mi = (const int*)maskp;
    const int lane = threadIdx.x & 63;
    bool clean = true;
#pragma unroll
    for (int k = 0; k < 4; ++k) {
        int v = mi[lane + 64 * k];
        clean = clean && (v == 0 || v == 1 || v == 0x3F800000);
    }
    unsigned long long bal = __ballot(clean);
    const bool byte_packed = (bal != 0xFFFFFFFFFFFFFFFFull);
    const bool obj = byte_packed ? (((const unsigned char*)maskp)[i] != 0)
                                 : (mi[i] != 0);

    // ---- load ray ----
    const float ox = cam[3 * i], oy = cam[3 * i + 1], oz = cam[3 * i + 2];
    const float dx = dirs[3 * i], dy = dirs[3 * i + 1], dz = dirs[3 * i + 2];

    // ---- _sphere_intersect (exact) ----
    float a  = dx * dx + dy * dy + dz * dz;
    float ob = ox * dx + oy * dy + oz * dz;
    float b  = 2.0f * ob;
    float oo = ox * ox + oy * oy + oz * oz;
    float c  = oo - 1.0f;
    float under = b * b - (4.0f * a) * c;
    const bool mask = under > 0.0f;
    float sq = __fsqrt_rn(fmaxf(under, 0.0f));
    float nearv = fmaxf(mask ? (-sq - b) * 0.5f : 0.0f, 0.01f);
    float farv  = fmaxf(mask ? ( sq - b) * 0.5f : 0.0f, 0.01f);

    // ---- _sphere_tracing: polynomial form along the ray ----
    // |o + t d|^2 == a t^2 + 2 ob t + oo exactly in reals; in-loop sdf uses
    // sqrt_native(fma chain) (error ~1e-7 abs vs reference order). Discrete
    // flips this can cause are confined to already-converged / tangent rays
    // with O(1e-3) output deltas. Final curr_pts recomputed exactly below.
    const float b2 = ob + ob;
    const float c2 = oo + 1e-12f;
    #define PSDF(t) (__builtin_amdgcn_sqrtf(fmaf(fmaf(a,(t),b2),(t),c2)) - 0.5f)

    bool unf_s = mask, unf_e = mask;
    float acc_s = nearv, acc_e = farv;
    float next_s = unf_s ? PSDF(nearv) : 0.0f;
    float next_e = unf_e ? PSDF(farv)  : 0.0f;

    for (int it = 0; it < 10; ++it) {
        float cs = unf_s ? next_s : 0.0f;
        cs = (cs <= 5e-5f) ? 0.0f : cs;
        unf_s = unf_s && (cs > 5e-5f);
        float ce = unf_e ? next_e : 0.0f;
        ce = (ce <= 5e-5f) ? 0.0f : ce;
        unf_e = unf_e && (ce > 5e-5f);

        acc_s = acc_s + cs;
        acc_e = acc_e - ce;
        next_s = unf_s ? PSDF(acc_s) : 0.0f;
        next_e = unf_e ? PSDF(acc_e) : 0.0f;

        bool nps = next_s < 0.0f;
        bool npe = next_e < 0.0f;
        float acc_s2 = acc_s - 0.5f * cs;
        float acc_e2 = acc_e + 0.5f * ce;
        float next_s2 = PSDF(acc_s2);
        float next_e2 = PSDF(acc_e2);
        acc_s  = nps ? acc_s2  : acc_s;
        next_s = nps ? next_s2 : next_s;
        acc_e  = npe ? acc_e2  : acc_e;
        next_e = npe ? next_e2 : next_e;

        bool ok = acc_s < acc_e;
        unf_s = unf_s && ok;
        unf_e = unf_e && ok;

        // Converged state is a fixpoint: skipping the rest is exact.
        if (!__any(unf_s || unf_e)) break;
    }
    { // trailing _upd_mask (mask bits only)
        float cs = unf_s ? next_s : 0.0f;
        cs = (cs <= 5e-5f) ? 0.0f : cs;
        unf_s = unf_s && (cs > 5e-5f);
        float ce = unf_e ? next_e : 0.0f;
        ce = (ce <= 5e-5f) ? 0.0f : ce;
        unf_e = unf_e && (ce > 5e-5f);
    }

    // Final curr_pts in exact reference op order (loop runs 10x uncond in ref,
    // so final curr = o + acc_s*d for every ray).
    const float csx = ox + acc_s * dx;
    const float csy = oy + acc_s * dy;
    const float csz = oz + acc_s * dz;

    const bool net0 = (acc_s < acc_e);
    const bool smask = unf_s;
    const float smin = smask ? acc_s : 0.0f;
    const float smax = smask ? acc_e : 0.0f;
    const float diff = smax - smin;
    const float denk = diff * DT;

    // ---- analytic sampler (exact-order verification at a small window) ----
    const float ZERO_HI = __uint_as_float(0x3E800001u);
    float ptsx = 0.0f, ptsy = 0.0f, ptsz = 0.0f, dist = 0.0f;
    bool hasNeg = false;

    if (__any(smask)) {
        float tstar = fast_div(-ob, a);             // parabola vertex
        float kf = (diff > 0.0f) ? fast_div(tstar - smin, denk) : 0.0f;
        kf = fminf(fmaxf(kf, 0.0f), 99.0f);
        int kv = (int)floorf(kf + 0.5f);
        int w0 = kv - 1; if (w0 < 0) w0 = 0;
        int w1 = kv + 1; if (w1 > 99) w1 = 99;

        int omin = w0; float vmin = 3.4e38f;
        for (int k = w0; k <= w1; ++k) {
            float vk = eval_k(k, smin, diff, ox, oy, oz, dx, dy, dz).v;
            if (vk < vmin) { vmin = vk; omin = k; }
        }
        hasNeg = vmin < 0.25f;

        int ind;
        if (hasNeg) {
            float v0 = eval_k(0, smin, diff, ox, oy, oz, dx, dy, dz).v;
            if (v0 < 0.25f) {
                ind = 0;
            } else {
                float cs25 = (oo + 1e-12f) - 0.25f;
                float disc = ob * ob - a * cs25;
                float r0 = fast_div(-ob - __fsqrt_rn(fmaxf(disc, 0.0f)), a);
                float kf0 = fast_div(r0 - smin, denk);
                if (!(kf0 >= 1.0f)) kf0 = 1.0f;     // NaN-safe clamp
                if (kf0 > 99.0f) kf0 = 99.0f;
                int start = (int)kf0 - 2; if (start < 1) start = 1;
                int kend = start + 5; if (kend > 99) kend = 99;
                int found = -1;
                float vprev = eval_k(start - 1, smin, diff, ox, oy, oz, dx, dy, dz).v;
                for (int k = start; k <= kend; ++k) {
                    float vk = eval_k(k, smin, diff, ox, oy, oz, dx, dy, dz).v;
                    if (vprev >= 0.25f && vk < 0.25f) { found = k; break; }
                    vprev = vk;
                }
                if (found < 0) {                    // rare fallback: exact scan
                    for (int k = 1; k <= 99; ++k) {
                        if (eval_k(k, smin, diff, ox, oy, oz, dx, dy, dz).v < 0.25f) {
                            found = k; break;
                        }
                    }
                    if (found < 0) found = omin;    // unreachable
                }
                ind = found;
            }
        } else if (vmin <= ZERO_HI) {               // sval==0 samples (~never)
            ind = 99;
            for (int k = 0; k <= 99; ++k) {
                if (eval_k(k, smin, diff, ox, oy, oz, dx, dy, dz).v <= ZERO_HI) {
                    ind = k; break;
                }
            }
        } else {
            ind = 99;
        }

        const int ilow = (ind > 0) ? ind - 1 : 0;
        SampleE eI = eval_k(ind,  smin, diff, ox, oy, oz, dx, dy, dz);
        SampleE eL = eval_k(ilow, smin, diff, ox, oy, oz, dx, dy, dz);

        ptsx = eI.px; ptsy = eI.py; ptsz = eI.pz;
        dist = eI.itv;

        const bool p_out = smask && !(obj && hasNeg);
        if (p_out) {
            SampleE eO = eval_k(omin, smin, diff, ox, oy, oz, dx, dy, dz);
            ptsx = eO.px; ptsy = eO.py; ptsz = eO.pz;
            dist = eO.itv;
        }

        // ---- secant (continuous output only: fast sqrt/div) ----
        const bool sec = smask && hasNeg && obj;
        if (__any(sec)) {
            float s_low  = sdf_fast(eL.px, eL.py, eL.pz);
            float s_high = sdf_fast(eI.px, eI.py, eI.pz);
            float z_low = eL.itv, z_high = eI.itv;
            float z = zpred_fast(s_low, s_high, z_low, z_high);
            for (int q = 0; q < 8; ++q) {
                float zx = ox + z * dx, zy = oy + z * dy, zz = oz + z * dz;
                float s = sdf_fast(zx, zy, zz);
                if (s > 0.0f) { z_low = z;  s_low = s; }
                if (s < 0.0f) { z_high = z; s_high = s; }
                z = zpred_fast(s_low, s_high, z_low, z_high);
            }
            if (sec) {
                ptsx = ox + z * dx; ptsy = oy + z * dy; ptsz = oz + z * dz;
                dist = z;
            }
        }
    }

    // ---- final merge & store ----
    float outx = smask ? ptsx : csx;
    float outy = smask ? ptsy : csy;
    float outz = smask ? ptsz : csz;
    float outnet = smask ? (hasNeg ? 1.0f : 0.0f) : (net0 ? 1.0f : 0.0f);
    float outdist = smask ? dist : acc_s;

    out[3 * i]     = outx;
    out[3 * i + 1] = outy;
    out[3 * i + 2] = outz;
    out[3 * NRAYS + i] = outnet;
    out[4 * NRAYS + i] = outdist;
}

extern "C" void kernel_launch(void* const* d_in, const int* in_sizes, int n_in,
                              void* d_out, int out_size, void* d_ws, size_t ws_size,
                              hipStream_t stream) {
    const float* cam  = (const float*)d_in[0];
    const float* dirs = (const float*)d_in[1];
    const void* maskp = d_in[2];
    float* out = (float*)d_out;
    dim3 grid(NRAYS / 256), block(256);
    raytrace_kernel<<<grid, block, 0, stream>>>(cam, dirs, maskp, out);
}